// Round 1
// baseline (1729.177 us; speedup 1.0000x reference)
//
#include <hip/hip_runtime.h>
#include <stdint.h>

// ---------- helpers ----------
typedef __attribute__((ext_vector_type(8))) short bf16x8;
typedef __attribute__((ext_vector_type(4))) float f32x4;

__device__ __forceinline__ float b2f(unsigned short s) {
    unsigned int u = ((unsigned int)s) << 16;
    return __builtin_bit_cast(float, u);
}
__device__ __forceinline__ unsigned short f2b(float f) {
    unsigned int u = __builtin_bit_cast(unsigned int, f);
    u += 0x7FFFu + ((u >> 16) & 1u);   // RNE
    return (unsigned short)(u >> 16);
}

// ---------- constants ----------
// B=64, N=4096, D=256, S=8, H=8, DH=32, ITERS=3
#define EPS_ATTN 1e-8f
#define LN_EPS 1e-5f
#define SCALE 0.0625f  // 256^-0.5

// ---------- prep: W2[kc][n][j] = bf16(cat(wk,wv)[kc*32+j][n]) ----------
__global__ __launch_bounds__(256) void k_prep(const float* __restrict__ wk,
                                              const float* __restrict__ wv,
                                              unsigned short* __restrict__ W2) {
    int g = blockIdx.x * 256 + threadIdx.x;   // 131072 total
    int j = g & 31;
    int n = (g >> 5) & 511;
    int kc = g >> 14;
    int k = kc * 32 + j;
    float v = (n < 256) ? wk[k * 256 + n] : wv[k * 256 + (n - 256)];
    W2[g] = f2b(v);
}

// ---------- slot init ----------
__global__ __launch_bounds__(256) void k_init(const float* __restrict__ sm,
                                              const float* __restrict__ slv,
                                              const float* __restrict__ noise,
                                              float* __restrict__ slots) {
    int idx = blockIdx.x * 256 + threadIdx.x; // 131072
    int d = idx & 255;
    slots[idx] = sm[d] + expf(slv[d]) * noise[idx];
}

// ---------- fused LN(inputs) + K/V projection (bf16 MFMA) ----------
// block: 64 rows x 512 cols (K cols 0..255 -> wk, 256..511 -> wv). 4096 blocks.
__global__ __launch_bounds__(256, 2) void k_kv(
    const float* __restrict__ x, const float* __restrict__ lnw, const float* __restrict__ lnb,
    const unsigned short* __restrict__ W2, const float* __restrict__ bk, const float* __restrict__ bv,
    unsigned short* __restrict__ Kb, unsigned short* __restrict__ Vb) {
    __shared__ unsigned short As[64 * 264];   // 33,792 B (stride 264: 2-way bank alias = free)
    __shared__ unsigned short Bs[256 * 40];   // 20,480 B
    int t = threadIdx.x;
    int w = t >> 6, lane = t & 63;
    int p = lane & 15, q = lane >> 4;

    // --- LN phase: wave w normalizes rows w*16..w*16+15 ---
    float4 lw = ((const float4*)lnw)[lane];
    float4 lb = ((const float4*)lnb)[lane];
    for (int i = 0; i < 16; ++i) {
        int r = w * 16 + i;
        size_t R = (size_t)blockIdx.x * 64 + r;
        float4 xv = ((const float4*)(x + R * 256))[lane];
        float s0 = xv.x + xv.y + xv.z + xv.w;
        float s1 = xv.x*xv.x + xv.y*xv.y + xv.z*xv.z + xv.w*xv.w;
        #pragma unroll
        for (int off = 1; off < 64; off <<= 1) {
            s0 += __shfl_xor(s0, off);
            s1 += __shfl_xor(s1, off);
        }
        float mean = s0 * (1.0f/256.0f);
        float var  = s1 * (1.0f/256.0f) - mean*mean;
        float rstd = rsqrtf(var + LN_EPS);
        ushort4 pk;
        pk.x = f2b((xv.x - mean) * rstd * lw.x + lb.x);
        pk.y = f2b((xv.y - mean) * rstd * lw.y + lb.y);
        pk.z = f2b((xv.z - mean) * rstd * lw.z + lb.z);
        pk.w = f2b((xv.w - mean) * rstd * lw.w + lb.w);
        *(ushort4*)(&As[r * 264 + lane * 4]) = pk;
    }
    __syncthreads();

    // --- GEMM phase ---
    f32x4 acc[32];
    f32x4 zero = {0.f, 0.f, 0.f, 0.f};
    #pragma unroll
    for (int i = 0; i < 32; ++i) acc[i] = zero;

    for (int kc = 0; kc < 8; ++kc) {
        bf16x8 af = *(const bf16x8*)(&As[(w*16 + p)*264 + kc*32 + q*8]);
        #pragma unroll
        for (int half = 0; half < 2; ++half) {
            __syncthreads();
            const uint4* src = (const uint4*)(W2 + ((kc*512 + half*256) << 5));
            #pragma unroll
            for (int j = 0; j < 4; ++j) {
                int f8 = t + j * 256;            // uint4 index; elements f8*8
                uint4 val = src[f8];
                *(uint4*)(&Bs[(f8 >> 2) * 40 + (f8 & 3) * 8]) = val;
            }
            __syncthreads();
            #pragma unroll
            for (int ntl = 0; ntl < 16; ++ntl) {
                bf16x8 bf = *(const bf16x8*)(&Bs[(ntl*16 + p)*40 + q*8]);
                acc[half*16 + ntl] = __builtin_amdgcn_mfma_f32_16x16x32_bf16(
                    af, bf, acc[half*16 + ntl], 0, 0, 0);
            }
        }
    }

    // --- store: K/V as bf16 [B,H,N,DH] ---
    int mb = blockIdx.x * 64 + w * 16 + q * 4;
    #pragma unroll
    for (int ai = 0; ai < 32; ++ai) {
        int c = ai * 16 + p;
        int cc = c & 255;
        float bias = (c < 256) ? bk[cc] : bv[cc];
        unsigned short* dst = (c < 256) ? Kb : Vb;
        int h = cc >> 5, dh = cc & 31;
        #pragma unroll
        for (int r = 0; r < 4; ++r) {
            int R = mb + r;
            int b_ = R >> 12, n = R & 4095;
            size_t idx = (((size_t)b_ * 8 + h) * 4096 + n) * 32 + dh;
            dst[idx] = f2b(acc[ai][r] + bias);
        }
    }
}

// ---------- q projection: LN(slots) @ wq + bq -> [B,H,S,DH] ----------
__global__ __launch_bounds__(256) void k_q(
    const float* __restrict__ slots, const float* __restrict__ lnw, const float* __restrict__ lnb,
    const float* __restrict__ wq, const float* __restrict__ bq, float* __restrict__ qg) {
    __shared__ float sln[256];
    __shared__ float red[8];
    int t = threadIdx.x;
    int row = blockIdx.x;                    // (b*8 + s), 512 rows
    float v = slots[(size_t)row * 256 + t];
    float s0 = v, s1 = v * v;
    #pragma unroll
    for (int off = 1; off < 64; off <<= 1) { s0 += __shfl_xor(s0, off); s1 += __shfl_xor(s1, off); }
    if ((t & 63) == 0) { red[t >> 6] = s0; red[4 + (t >> 6)] = s1; }
    __syncthreads();
    float ts0 = red[0] + red[1] + red[2] + red[3];
    float ts1 = red[4] + red[5] + red[6] + red[7];
    float mean = ts0 * (1.f/256.f);
    float var  = ts1 * (1.f/256.f) - mean * mean;
    float rstd = rsqrtf(var + LN_EPS);
    sln[t] = (v - mean) * rstd * lnw[t] + lnb[t];
    __syncthreads();
    float acc = bq[t];
    #pragma unroll 4
    for (int k = 0; k < 256; ++k) acc += sln[k] * wq[k * 256 + t];
    int b = row >> 3, sl = row & 7;
    qg[(size_t)b * 2048 + (t >> 5) * 256 + sl * 32 + (t & 31)] = acc;
}

// ---------- attention sweep ----------
// grid 4096 = 512 (b,h) x 8 N-splits; block streams 512 n in 8 chunks of 64.
__global__ __launch_bounds__(256) void k_attn(
    const unsigned short* __restrict__ Kg, const unsigned short* __restrict__ Vg,
    const float* __restrict__ qg, float* __restrict__ upd_raw, float* __restrict__ rowsum,
    float* __restrict__ attn_out, int last) {
    __shared__ float Kl[64 * 33];
    __shared__ float Vl[64 * 33];
    __shared__ float al[8 * 72];
    int t = threadIdx.x;
    int bh = blockIdx.x >> 3;
    int n0 = (blockIdx.x & 7) * 512;
    int s1i = t & 7, nl0 = t >> 3;       // dot stage mapping
    int su = t >> 5, du = t & 31;        // upd stage mapping
    int nlK = t >> 2, dK = (t & 3) * 8;  // staging mapping

    float q_r[32];
    #pragma unroll
    for (int d = 0; d < 32; ++d) q_r[d] = qg[bh * 256 + s1i * 32 + d];

    float uacc = 0.f;
    float rs_loc[8];
    #pragma unroll
    for (int s = 0; s < 8; ++s) rs_loc[s] = 0.f;

    for (int ci = 0; ci < 8; ++ci) {
        int nb = n0 + ci * 64;
        __syncthreads();
        {   // stage K,V chunk [64][32] -> fp32 LDS (pad 33, conflict-free)
            size_t base = ((size_t)bh * 4096 + nb) * 32;
            uint4 kv = ((const uint4*)(Kg + base))[t];
            uint4 vv = ((const uint4*)(Vg + base))[t];
            const unsigned short* ku = (const unsigned short*)&kv;
            const unsigned short* vu = (const unsigned short*)&vv;
            #pragma unroll
            for (int j = 0; j < 8; ++j) {
                Kl[nlK * 33 + dK + j] = b2f(ku[j]);
                Vl[nlK * 33 + dK + j] = b2f(vu[j]);
            }
        }
        __syncthreads();
        {   // dots: thread -> (s, nl) and (s, nl+32)
            float a0 = 0.f, a1 = 0.f;
            #pragma unroll
            for (int d = 0; d < 32; ++d) {
                a0 += Kl[nl0 * 33 + d] * q_r[d];
                a1 += Kl[(nl0 + 32) * 33 + d] * q_r[d];
            }
            al[s1i * 72 + nl0]      = a0 * SCALE;
            al[s1i * 72 + nl0 + 32] = a1 * SCALE;
        }
        __syncthreads();
        if (t < 64) {   // softmax over slot axis per n
            float av[8];
            float m = -1e30f;
            #pragma unroll
            for (int s = 0; s < 8; ++s) { av[s] = al[s * 72 + t]; m = fmaxf(m, av[s]); }
            float sum = 0.f;
            #pragma unroll
            for (int s = 0; s < 8; ++s) { av[s] = expf(av[s] - m); sum += av[s]; }
            float inv = 1.0f / sum;
            #pragma unroll
            for (int s = 0; s < 8; ++s) {
                float a = av[s] * inv + EPS_ATTN;
                al[s * 72 + t] = a;
                rs_loc[s] += a;
                if (last) attn_out[((size_t)bh * 8 + s) * 4096 + nb + t] = a;
            }
        }
        __syncthreads();
        {   // upd accumulation: thread -> (s, d)
            #pragma unroll
            for (int j = 0; j < 64; ++j) uacc += al[su * 72 + j] * Vl[j * 33 + du];
        }
    }
    atomicAdd(&upd_raw[bh * 256 + su * 32 + du], uacc);
    if (t < 64) {
        #pragma unroll
        for (int s = 0; s < 8; ++s) {
            float v = rs_loc[s];
            #pragma unroll
            for (int off = 1; off < 64; off <<= 1) v += __shfl_xor(v, off);
            if (t == 0) atomicAdd(&rowsum[bh * 8 + s], v);
        }
    }
}

// ---------- slot update: wo-proj + GRU + FF. one block per batch (8 rows) ----------
__global__ __launch_bounds__(256) void k_slot(
    float* __restrict__ slots, const float* __restrict__ upd_raw, const float* __restrict__ rowsum,
    const float* __restrict__ wo, const float* __restrict__ bo,
    const float* __restrict__ wih, const float* __restrict__ bih,
    const float* __restrict__ whh, const float* __restrict__ bhh,
    const float* __restrict__ w1, const float* __restrict__ b1,
    const float* __restrict__ w2, const float* __restrict__ b2,
    const float* __restrict__ lnfw, const float* __restrict__ lnfb,
    float* __restrict__ out_slots, int last) {
    __shared__ float U[8][256], Hp[8][256], O[8][256], S1[8][256], F[8][256], H1[8][256];
    int t = threadIdx.x;
    int b = blockIdx.x;
    int h = t >> 5, dh = t & 31;

    for (int r = 0; r < 8; ++r) {
        Hp[r][t] = slots[((size_t)b * 8 + r) * 256 + t];
        float rs = fmaxf(rowsum[(b * 8 + h) * 8 + r], 1e-12f);
        U[r][t] = upd_raw[(size_t)(b * 8 + h) * 256 + r * 32 + dh] / rs;
    }
    __syncthreads();

    // o = U @ wo + bo
    float ao[8];
    #pragma unroll
    for (int r = 0; r < 8; ++r) ao[r] = 0.f;
    #pragma unroll 2
    for (int k = 0; k < 256; ++k) {
        float wv_ = wo[k * 256 + t];
        #pragma unroll
        for (int r = 0; r < 8; ++r) ao[r] += U[r][k] * wv_;
    }
    float bov = bo[t];
    #pragma unroll
    for (int r = 0; r < 8; ++r) O[r][t] = ao[r] + bov;
    __syncthreads();

    // GRU gates (torch order r,z,n)
    float ax0[8], ax1[8], ax2[8], ah0[8], ah1[8], ah2[8];
    #pragma unroll
    for (int r = 0; r < 8; ++r) { ax0[r]=ax1[r]=ax2[r]=ah0[r]=ah1[r]=ah2[r]=0.f; }
    for (int k = 0; k < 256; ++k) {
        float wx0 = wih[k * 768 + t], wx1 = wih[k * 768 + 256 + t], wx2 = wih[k * 768 + 512 + t];
        float wh0 = whh[k * 768 + t], wh1 = whh[k * 768 + 256 + t], wh2 = whh[k * 768 + 512 + t];
        #pragma unroll
        for (int r = 0; r < 8; ++r) {
            float ov = O[r][k], hv = Hp[r][k];
            ax0[r] += ov * wx0; ax1[r] += ov * wx1; ax2[r] += ov * wx2;
            ah0[r] += hv * wh0; ah1[r] += hv * wh1; ah2[r] += hv * wh2;
        }
    }
    float bx0 = bih[t], bx1 = bih[256 + t], bx2 = bih[512 + t];
    float bh0 = bhh[t], bh1 = bhh[256 + t], bh2 = bhh[512 + t];
    #pragma unroll
    for (int r = 0; r < 8; ++r) {
        float rg = 1.f / (1.f + expf(-(ax0[r] + bx0 + ah0[r] + bh0)));
        float zg = 1.f / (1.f + expf(-(ax1[r] + bx1 + ah1[r] + bh1)));
        float ng = tanhf(ax2[r] + bx2 + rg * (ah2[r] + bh2));
        S1[r][t] = (1.f - zg) * ng + zg * Hp[r][t];
    }
    __syncthreads();

    // LN per row (wave handles 2 rows)
    {
        int wv_ = t >> 6, lane = t & 63;
        for (int rr = 0; rr < 2; ++rr) {
            int r = wv_ * 2 + rr;
            float vals[4]; float s0 = 0.f, sq = 0.f;
            #pragma unroll
            for (int j = 0; j < 4; ++j) { vals[j] = S1[r][lane + 64 * j]; s0 += vals[j]; sq += vals[j] * vals[j]; }
            #pragma unroll
            for (int off = 1; off < 64; off <<= 1) { s0 += __shfl_xor(s0, off); sq += __shfl_xor(sq, off); }
            float mean = s0 * (1.f/256.f);
            float var  = sq * (1.f/256.f) - mean * mean;
            float rstd = rsqrtf(var + LN_EPS);
            #pragma unroll
            for (int j = 0; j < 4; ++j) {
                int c = lane + 64 * j;
                F[r][c] = (vals[j] - mean) * rstd * lnfw[c] + lnfb[c];
            }
        }
    }
    __syncthreads();

    // ff1 = relu(F @ w1 + b1)
    float a1[8];
    #pragma unroll
    for (int r = 0; r < 8; ++r) a1[r] = 0.f;
    #pragma unroll 2
    for (int k = 0; k < 256; ++k) {
        float wv_ = w1[k * 256 + t];
        #pragma unroll
        for (int r = 0; r < 8; ++r) a1[r] += F[r][k] * wv_;
    }
    float b1v = b1[t];
    #pragma unroll
    for (int r = 0; r < 8; ++r) H1[r][t] = fmaxf(a1[r] + b1v, 0.f);
    __syncthreads();

    // ff2 + residual
    float a2[8];
    #pragma unroll
    for (int r = 0; r < 8; ++r) a2[r] = 0.f;
    #pragma unroll 2
    for (int k = 0; k < 256; ++k) {
        float wv_ = w2[k * 256 + t];
        #pragma unroll
        for (int r = 0; r < 8; ++r) a2[r] += H1[r][k] * wv_;
    }
    float b2v = b2[t];
    #pragma unroll
    for (int r = 0; r < 8; ++r) {
        float fin = S1[r][t] + a2[r] + b2v;
        slots[((size_t)b * 8 + r) * 256 + t] = fin;
        if (last) out_slots[((size_t)b * 8 + r) * 256 + t] = fin;
    }
}

// ---------- final attn normalization ----------
__global__ __launch_bounds__(256) void k_scale(float* __restrict__ attn, const float* __restrict__ rowsum) {
    size_t idx = (size_t)blockIdx.x * 256 + threadIdx.x;  // 16,777,216
    int row = (int)(idx >> 12);
    float rs = fmaxf(rowsum[row], 1e-12f);
    attn[idx] = attn[idx] / rs;
}

extern "C" void kernel_launch(void* const* d_in, const int* in_sizes, int n_in,
                              void* d_out, int out_size, void* d_ws, size_t ws_size,
                              hipStream_t stream) {
    const float* inputs = (const float*)d_in[0];
    const float* noise  = (const float*)d_in[1];
    const float* sm     = (const float*)d_in[2];
    const float* slv    = (const float*)d_in[3];
    const float* wq     = (const float*)d_in[4];
    const float* bq     = (const float*)d_in[5];
    const float* wk     = (const float*)d_in[6];
    const float* bk     = (const float*)d_in[7];
    const float* wv     = (const float*)d_in[8];
    const float* bv     = (const float*)d_in[9];
    const float* wo     = (const float*)d_in[10];
    const float* bo     = (const float*)d_in[11];
    const float* wih    = (const float*)d_in[12];
    const float* bih    = (const float*)d_in[13];
    const float* whh    = (const float*)d_in[14];
    const float* bhh    = (const float*)d_in[15];
    const float* w1     = (const float*)d_in[16];
    const float* b1     = (const float*)d_in[17];
    const float* w2     = (const float*)d_in[18];
    const float* b2     = (const float*)d_in[19];
    const float* lniw   = (const float*)d_in[20];
    const float* lnib   = (const float*)d_in[21];
    const float* lnsw   = (const float*)d_in[22];
    const float* lnsb   = (const float*)d_in[23];
    const float* lnfw   = (const float*)d_in[24];
    const float* lnfb   = (const float*)d_in[25];

    // ws layout (258 MB total)
    char* ws = (char*)d_ws;
    unsigned short* Kb = (unsigned short*)ws;                         // 134,217,728 B
    unsigned short* Vb = (unsigned short*)(ws + 134217728ull);        // 134,217,728 B
    unsigned short* W2 = (unsigned short*)(ws + 268435456ull);        //     262,144 B
    float* slots   = (float*)(ws + 268697600ull);                     //     524,288 B
    float* qg      = (float*)(ws + 269221888ull);                     //     524,288 B
    float* upd_raw = (float*)(ws + 269746176ull);                     //     524,288 B
    float* rowsum  = (float*)(ws + 270270464ull);                     //      16,384 B

    float* out_slots = (float*)d_out;            // [64,8,256]
    float* attn_out  = (float*)d_out + 131072;   // [64,8,8,4096]

    k_prep<<<512, 256, 0, stream>>>(wk, wv, W2);
    k_init<<<512, 256, 0, stream>>>(sm, slv, noise, slots);
    k_kv<<<4096, 256, 0, stream>>>(inputs, lniw, lnib, W2, bk, bv, Kb, Vb);
    for (int it = 0; it < 3; ++it) {
        int last = (it == 2);
        hipMemsetAsync(upd_raw, 0, 524288 + 16384, stream);
        k_q<<<512, 256, 0, stream>>>(slots, lnsw, lnsb, wq, bq, qg);
        k_attn<<<4096, 256, 0, stream>>>(Kb, Vb, qg, upd_raw, rowsum, attn_out, last);
        k_slot<<<64, 256, 0, stream>>>(slots, upd_raw, rowsum, wo, bo, wih, bih, whh, bhh,
                                       w1, b1, w2, b2, lnfw, lnfb, out_slots, last);
    }
    k_scale<<<65536, 256, 0, stream>>>(attn_out, rowsum);
}

// Round 2
// 1575.707 us; speedup vs baseline: 1.0974x; 1.0974x over previous
//
#include <hip/hip_runtime.h>
#include <stdint.h>

// ---------- helpers ----------
typedef __attribute__((ext_vector_type(8))) short bf16x8;
typedef __attribute__((ext_vector_type(4))) float f32x4;

__device__ __forceinline__ float b2f(unsigned short s) {
    unsigned int u = ((unsigned int)s) << 16;
    return __builtin_bit_cast(float, u);
}
__device__ __forceinline__ unsigned short f2b(float f) {
    unsigned int u = __builtin_bit_cast(unsigned int, f);
    u += 0x7FFFu + ((u >> 16) & 1u);   // RNE
    return (unsigned short)(u >> 16);
}
__device__ __forceinline__ void unpack8(uint4 u, float* o) {
    unsigned int a0 = u.x, a1 = u.y, a2 = u.z, a3 = u.w;
    o[0] = __builtin_bit_cast(float, a0 << 16);
    o[1] = __builtin_bit_cast(float, a0 & 0xffff0000u);
    o[2] = __builtin_bit_cast(float, a1 << 16);
    o[3] = __builtin_bit_cast(float, a1 & 0xffff0000u);
    o[4] = __builtin_bit_cast(float, a2 << 16);
    o[5] = __builtin_bit_cast(float, a2 & 0xffff0000u);
    o[6] = __builtin_bit_cast(float, a3 << 16);
    o[7] = __builtin_bit_cast(float, a3 & 0xffff0000u);
}

#define GLOAD_LDS16(g, l) __builtin_amdgcn_global_load_lds( \
    (const __attribute__((address_space(1))) unsigned int*)(g), \
    (__attribute__((address_space(3))) unsigned int*)(l), 16, 0, 0)

// ---------- constants ----------
#define EPS_ATTN 1e-8f
#define LN_EPS 1e-5f
#define SCALE 0.0625f  // 256^-0.5

// ---------- prep: W3 in MFMA B-fragment order ----------
// W3[stage][frag f][j]: stage = kc*2+half (16), f = ntl*64 + q*16 + p (1024), j (8)
// element: k = kc*32 + q*8 + j, n = half*256 + ntl*16 + p, from cat(wk,wv)[k][n]
__global__ __launch_bounds__(256) void k_prep(const float* __restrict__ wk,
                                              const float* __restrict__ wv,
                                              unsigned short* __restrict__ W3) {
    int g = blockIdx.x * 256 + threadIdx.x;   // 131072
    int j = g & 7;
    int f = (g >> 3) & 1023;
    int stage = g >> 13;
    int p = f & 15, qq = (f >> 4) & 3, ntl = f >> 6;
    int kc = stage >> 1, half = stage & 1;
    int k = kc * 32 + qq * 8 + j;
    int n = half * 256 + ntl * 16 + p;
    float v = (n < 256) ? wk[k * 256 + n] : wv[k * 256 + (n - 256)];
    W3[g] = f2b(v);
}

// ---------- slot init ----------
__global__ __launch_bounds__(256) void k_init(const float* __restrict__ sm,
                                              const float* __restrict__ slv,
                                              const float* __restrict__ noise,
                                              float* __restrict__ slots) {
    int idx = blockIdx.x * 256 + threadIdx.x; // 131072
    int d = idx & 255;
    slots[idx] = sm[d] + expf(slv[d]) * noise[idx];
}

// ---------- fused LN(inputs) + K/V projection (bf16 MFMA, async B staging) ----------
// block 256 thr (4 waves): 64 rows x 512 cols. 4096 blocks. Each wave: 16 rows x all 512 cols.
__global__ __launch_bounds__(256, 2) void k_kv(
    const float* __restrict__ x, const float* __restrict__ lnw, const float* __restrict__ lnb,
    const unsigned short* __restrict__ W3, const float* __restrict__ bk, const float* __restrict__ bv,
    unsigned short* __restrict__ Kb, unsigned short* __restrict__ Vb) {
    __shared__ __align__(16) unsigned short sh[33792];  // 67,584 B
    unsigned short* As = sh;                  // 16384 ushorts (A frags, xor-swizzled)
    unsigned short* Bs = sh + 16384;          // 2 x 8192 ushorts (B dbuf)
    float* bL = (float*)(sh + 32768);         // 512 floats (biases)
    int t = threadIdx.x;
    int w = t >> 6, lane = t & 63;
    int p = lane & 15, q = lane >> 4;

    // issue stage-0 B loads (async, direct to LDS; lds dest = base + lane*16B)
    {
        const unsigned short* gp = W3 + (size_t)(w * 4) * 512 + lane * 8;
        #pragma unroll
        for (int c = 0; c < 4; ++c)
            GLOAD_LDS16(gp + c * 512, Bs + (w * 4 + c) * 512);
    }

    // bias staging
    if (t < 128) {
        float4 bb = (t < 64) ? ((const float4*)bk)[t] : ((const float4*)bv)[t - 64];
        *(float4*)&bL[t * 4] = bb;
    }

    // --- LN: wave w rows w*16..w*16+15, all 16 row-loads prefetched ---
    float4 lw  = ((const float4*)lnw)[lane];
    float4 lbv = ((const float4*)lnb)[lane];
    float4 xv[16];
    const float* xbase = x + ((size_t)blockIdx.x * 64 + w * 16) * 256;
    #pragma unroll
    for (int i = 0; i < 16; ++i) xv[i] = ((const float4*)(xbase + i * 256))[lane];
    int kcw = lane >> 3, qw = (lane >> 1) & 3, j0 = (lane & 1) * 4;
    #pragma unroll
    for (int i = 0; i < 16; ++i) {
        float4 v = xv[i];
        float s0 = v.x + v.y + v.z + v.w;
        float s1 = v.x * v.x + v.y * v.y + v.z * v.z + v.w * v.w;
        #pragma unroll
        for (int o = 1; o < 64; o <<= 1) { s0 += __shfl_xor(s0, o); s1 += __shfl_xor(s1, o); }
        float mean = s0 * (1.0f / 256.0f);
        float var  = s1 * (1.0f / 256.0f) - mean * mean;
        float rstd = rsqrtf(var + LN_EPS);
        ushort4 pk;
        pk.x = f2b((v.x - mean) * rstd * lw.x + lbv.x);
        pk.y = f2b((v.y - mean) * rstd * lw.y + lbv.y);
        pk.z = f2b((v.z - mean) * rstd * lw.z + lbv.z);
        pk.w = f2b((v.w - mean) * rstd * lw.w + lbv.w);
        int pos = (qw * 16 + i) ^ kcw;   // xor swizzle spreads writer banks across kc
        *(ushort4*)&As[((w * 8 + kcw) * 64 + pos) * 8 + j0] = pk;
    }
    __syncthreads();   // drains stage-0 vmcnt too

    // --- GEMM: 16 stages (kc-half), B double-buffered ---
    f32x4 acc[32];
    f32x4 zero = {0.f, 0.f, 0.f, 0.f};
    #pragma unroll
    for (int i = 0; i < 32; ++i) acc[i] = zero;

    for (int s1 = 0; s1 < 16; ++s1) {
        if (s1 < 15) {
            int nx = s1 + 1;
            const unsigned short* gp = W3 + (size_t)nx * 8192 + (w * 4) * 512 + lane * 8;
            unsigned short* lb = Bs + ((nx & 1) ? 8192 : 0);
            #pragma unroll
            for (int c = 0; c < 4; ++c)
                GLOAD_LDS16(gp + c * 512, lb + (w * 4 + c) * 512);
        }
        int kc = s1 >> 1, half = s1 & 1;
        bf16x8 af = *(const bf16x8*)&As[((w * 8 + kc) * 64 + ((q * 16 + p) ^ kc)) * 8];
        const unsigned short* bbuf = Bs + ((s1 & 1) ? 8192 : 0);
        #pragma unroll
        for (int ntl = 0; ntl < 16; ++ntl) {
            bf16x8 bf = *(const bf16x8*)&bbuf[ntl * 512 + lane * 8];  // lane-contiguous b128
            acc[half * 16 + ntl] = __builtin_amdgcn_mfma_f32_16x16x32_bf16(
                af, bf, acc[half * 16 + ntl], 0, 0, 0);
        }
        __syncthreads();
    }

    // --- epilogue: repack via LDS, 16B-coalesced stores. K layout [B,H,N,DH] bf16 ---
    unsigned short* rep = As;   // reuse (32 KB)
    int b_   = blockIdx.x >> 6;
    int n0g  = (blockIdx.x & 63) * 64;
    #pragma unroll
    for (int hf = 0; hf < 2; ++hf) {
        if (hf) __syncthreads();
        #pragma unroll
        for (int al = 0; al < 16; ++al) {
            int ai = hf * 16 + al;
            float bias = bL[hf * 256 + al * 16 + p];
            int hl = al >> 1, dh = (al & 1) * 16 + p;
            #pragma unroll
            for (int r = 0; r < 4; ++r) {
                int nl = w * 16 + q * 4 + r;
                rep[(hl * 64 + nl) * 32 + dh] = f2b(acc[ai][r] + bias);
            }
        }
        __syncthreads();
        unsigned short* dst = hf ? Vb : Kb;
        #pragma unroll
        for (int i = 0; i < 8; ++i) {
            uint4 vd = *(const uint4*)&rep[(i * 256 + t) * 8];
            *(uint4*)(dst + (((size_t)b_ * 8 + i) * 4096 + n0g) * 32 + t * 8) = vd;
        }
    }
}

// ---------- q projection: LN(slots) @ wq + bq -> [B,H,S,DH] ----------
__global__ __launch_bounds__(256) void k_q(
    const float* __restrict__ slots, const float* __restrict__ lnw, const float* __restrict__ lnb,
    const float* __restrict__ wq, const float* __restrict__ bq, float* __restrict__ qg) {
    __shared__ float sln[256];
    __shared__ float red[8];
    int t = threadIdx.x;
    int row = blockIdx.x;                    // (b*8 + s), 512 rows
    float v = slots[(size_t)row * 256 + t];
    float s0 = v, s1 = v * v;
    #pragma unroll
    for (int off = 1; off < 64; off <<= 1) { s0 += __shfl_xor(s0, off); s1 += __shfl_xor(s1, off); }
    if ((t & 63) == 0) { red[t >> 6] = s0; red[4 + (t >> 6)] = s1; }
    __syncthreads();
    float ts0 = red[0] + red[1] + red[2] + red[3];
    float ts1 = red[4] + red[5] + red[6] + red[7];
    float mean = ts0 * (1.f / 256.f);
    float var  = ts1 * (1.f / 256.f) - mean * mean;
    float rstd = rsqrtf(var + LN_EPS);
    sln[t] = (v - mean) * rstd * lnw[t] + lnb[t];
    __syncthreads();
    float acc = bq[t];
    #pragma unroll 4
    for (int k = 0; k < 256; ++k) acc += sln[k] * wq[k * 256 + t];
    int b = row >> 3, sl = row & 7;
    qg[(size_t)b * 2048 + (t >> 5) * 256 + sl * 32 + (t & 31)] = acc;
}

// ---------- attention sweep: thread-per-n, K in registers ----------
// grid 4096 = 512 (b,h) x 8 N-splits; block covers 512 n in 2 stages of 256.
__global__ __launch_bounds__(256, 3) void k_attn(
    const unsigned short* __restrict__ Kg, const unsigned short* __restrict__ Vg,
    const float* __restrict__ qg, float* __restrict__ upd_raw, float* __restrict__ rowsum,
    float* __restrict__ attn_out, int last) {
    __shared__ __align__(16) float VL[256 * 33];  // pad 33: conflict-free
    __shared__ __align__(16) float aL[8 * 264];
    __shared__ float qL[256];
    int t = threadIdx.x;
    int bh = blockIdx.x >> 3;
    int n0 = (blockIdx.x & 7) * 512;
    qL[t] = qg[bh * 256 + t];
    int s2 = t >> 5, dq = (t >> 2) & 7, jp = t & 3;   // upd mapping
    float4 uacc = {0.f, 0.f, 0.f, 0.f};
    float rs_loc[8];
    #pragma unroll
    for (int s = 0; s < 8; ++s) rs_loc[s] = 0.f;
    __syncthreads();

    for (int st = 0; st < 2; ++st) {
        int n = n0 + st * 256 + t;
        size_t base = ((size_t)bh * 4096 + n) * 32;
        // K row in registers
        const uint4* kp = (const uint4*)(Kg + base);
        float kf[32];
        unpack8(kp[0], kf + 0); unpack8(kp[1], kf + 8);
        unpack8(kp[2], kf + 16); unpack8(kp[3], kf + 24);
        // dots vs all 8 slots (q broadcast from LDS)
        float sd[8];
        #pragma unroll
        for (int s = 0; s < 8; ++s) {
            float a = 0.f;
            #pragma unroll
            for (int d4 = 0; d4 < 8; ++d4) {
                float4 q4 = *(const float4*)&qL[s * 32 + d4 * 4];
                a = fmaf(kf[d4 * 4 + 0], q4.x, a);
                a = fmaf(kf[d4 * 4 + 1], q4.y, a);
                a = fmaf(kf[d4 * 4 + 2], q4.z, a);
                a = fmaf(kf[d4 * 4 + 3], q4.w, a);
            }
            sd[s] = a * SCALE;
        }
        // softmax over slot axis (fully per-thread)
        float m = sd[0];
        #pragma unroll
        for (int s = 1; s < 8; ++s) m = fmaxf(m, sd[s]);
        float e[8]; float sum = 0.f;
        #pragma unroll
        for (int s = 0; s < 8; ++s) { e[s] = __expf(sd[s] - m); sum += e[s]; }
        float inv = 1.0f / sum;
        float a8[8];
        #pragma unroll
        for (int s = 0; s < 8; ++s) { a8[s] = e[s] * inv + EPS_ATTN; rs_loc[s] += a8[s]; }
        if (last) {
            #pragma unroll
            for (int s = 0; s < 8; ++s)
                attn_out[((size_t)bh * 8 + s) * 4096 + n] = a8[s];
        }
        if (st) __syncthreads();   // protect LDS from previous stage's readers
        #pragma unroll
        for (int s = 0; s < 8; ++s) aL[s * 264 + t] = a8[s];
        // V row -> LDS
        const uint4* vp = (const uint4*)(Vg + base);
        float vf[32];
        unpack8(vp[0], vf + 0); unpack8(vp[1], vf + 8);
        unpack8(vp[2], vf + 16); unpack8(vp[3], vf + 24);
        #pragma unroll
        for (int d = 0; d < 32; ++d) VL[t * 33 + d] = vf[d];
        __syncthreads();
        // upd partial: thread (s2, dq, jp); j = j2*4+jp keeps banks distinct
        #pragma unroll 4
        for (int j2 = 0; j2 < 64; ++j2) {
            int j = j2 * 4 + jp;
            float av = aL[s2 * 264 + j];
            int vb = j * 33 + dq * 4;
            uacc.x = fmaf(av, VL[vb + 0], uacc.x);
            uacc.y = fmaf(av, VL[vb + 1], uacc.y);
            uacc.z = fmaf(av, VL[vb + 2], uacc.z);
            uacc.w = fmaf(av, VL[vb + 3], uacc.w);
        }
    }
    // reduce over jp (lane bits 0-1)
    uacc.x += __shfl_xor(uacc.x, 1); uacc.x += __shfl_xor(uacc.x, 2);
    uacc.y += __shfl_xor(uacc.y, 1); uacc.y += __shfl_xor(uacc.y, 2);
    uacc.z += __shfl_xor(uacc.z, 1); uacc.z += __shfl_xor(uacc.z, 2);
    uacc.w += __shfl_xor(uacc.w, 1); uacc.w += __shfl_xor(uacc.w, 2);
    if (jp == 0) {
        float* up = upd_raw + bh * 256 + s2 * 32 + dq * 4;
        atomicAdd(up + 0, uacc.x);
        atomicAdd(up + 1, uacc.y);
        atomicAdd(up + 2, uacc.z);
        atomicAdd(up + 3, uacc.w);
    }
    #pragma unroll
    for (int s = 0; s < 8; ++s) {
        float v = rs_loc[s];
        #pragma unroll
        for (int o = 1; o < 64; o <<= 1) v += __shfl_xor(v, o);
        if ((t & 63) == 0) atomicAdd(&rowsum[bh * 8 + s], v);
    }
}

// ---------- slot update: wo-proj + GRU + FF. one block per batch (8 rows) ----------
__global__ __launch_bounds__(256) void k_slot(
    float* __restrict__ slots, const float* __restrict__ upd_raw, const float* __restrict__ rowsum,
    const float* __restrict__ wo, const float* __restrict__ bo,
    const float* __restrict__ wih, const float* __restrict__ bih,
    const float* __restrict__ whh, const float* __restrict__ bhh,
    const float* __restrict__ w1, const float* __restrict__ b1,
    const float* __restrict__ w2, const float* __restrict__ b2,
    const float* __restrict__ lnfw, const float* __restrict__ lnfb,
    float* __restrict__ out_slots, int last) {
    __shared__ float U[8][256], Hp[8][256], O[8][256], S1[8][256], F[8][256], H1[8][256];
    int t = threadIdx.x;
    int b = blockIdx.x;
    int h = t >> 5, dh = t & 31;

    for (int r = 0; r < 8; ++r) {
        Hp[r][t] = slots[((size_t)b * 8 + r) * 256 + t];
        float rs = fmaxf(rowsum[(b * 8 + h) * 8 + r], 1e-12f);
        U[r][t] = upd_raw[(size_t)(b * 8 + h) * 256 + r * 32 + dh] / rs;
    }
    __syncthreads();

    float ao[8];
    #pragma unroll
    for (int r = 0; r < 8; ++r) ao[r] = 0.f;
    #pragma unroll 2
    for (int k = 0; k < 256; ++k) {
        float wv_ = wo[k * 256 + t];
        #pragma unroll
        for (int r = 0; r < 8; ++r) ao[r] += U[r][k] * wv_;
    }
    float bov = bo[t];
    #pragma unroll
    for (int r = 0; r < 8; ++r) O[r][t] = ao[r] + bov;
    __syncthreads();

    float ax0[8], ax1[8], ax2[8], ah0[8], ah1[8], ah2[8];
    #pragma unroll
    for (int r = 0; r < 8; ++r) { ax0[r]=ax1[r]=ax2[r]=ah0[r]=ah1[r]=ah2[r]=0.f; }
    for (int k = 0; k < 256; ++k) {
        float wx0 = wih[k * 768 + t], wx1 = wih[k * 768 + 256 + t], wx2 = wih[k * 768 + 512 + t];
        float wh0 = whh[k * 768 + t], wh1 = whh[k * 768 + 256 + t], wh2 = whh[k * 768 + 512 + t];
        #pragma unroll
        for (int r = 0; r < 8; ++r) {
            float ov = O[r][k], hv = Hp[r][k];
            ax0[r] += ov * wx0; ax1[r] += ov * wx1; ax2[r] += ov * wx2;
            ah0[r] += hv * wh0; ah1[r] += hv * wh1; ah2[r] += hv * wh2;
        }
    }
    float bx0 = bih[t], bx1 = bih[256 + t], bx2 = bih[512 + t];
    float bh0 = bhh[t], bh1 = bhh[256 + t], bh2 = bhh[512 + t];
    #pragma unroll
    for (int r = 0; r < 8; ++r) {
        float rg = 1.f / (1.f + expf(-(ax0[r] + bx0 + ah0[r] + bh0)));
        float zg = 1.f / (1.f + expf(-(ax1[r] + bx1 + ah1[r] + bh1)));
        float ng = tanhf(ax2[r] + bx2 + rg * (ah2[r] + bh2));
        S1[r][t] = (1.f - zg) * ng + zg * Hp[r][t];
    }
    __syncthreads();

    {
        int wv_ = t >> 6, lane = t & 63;
        for (int rr = 0; rr < 2; ++rr) {
            int r = wv_ * 2 + rr;
            float vals[4]; float s0 = 0.f, sq = 0.f;
            #pragma unroll
            for (int j = 0; j < 4; ++j) { vals[j] = S1[r][lane + 64 * j]; s0 += vals[j]; sq += vals[j] * vals[j]; }
            #pragma unroll
            for (int off = 1; off < 64; off <<= 1) { s0 += __shfl_xor(s0, off); sq += __shfl_xor(sq, off); }
            float mean = s0 * (1.f / 256.f);
            float var  = sq * (1.f / 256.f) - mean * mean;
            float rstd = rsqrtf(var + LN_EPS);
            #pragma unroll
            for (int j = 0; j < 4; ++j) {
                int c = lane + 64 * j;
                F[r][c] = (vals[j] - mean) * rstd * lnfw[c] + lnfb[c];
            }
        }
    }
    __syncthreads();

    float a1[8];
    #pragma unroll
    for (int r = 0; r < 8; ++r) a1[r] = 0.f;
    #pragma unroll 2
    for (int k = 0; k < 256; ++k) {
        float wv_ = w1[k * 256 + t];
        #pragma unroll
        for (int r = 0; r < 8; ++r) a1[r] += F[r][k] * wv_;
    }
    float b1v = b1[t];
    #pragma unroll
    for (int r = 0; r < 8; ++r) H1[r][t] = fmaxf(a1[r] + b1v, 0.f);
    __syncthreads();

    float a2[8];
    #pragma unroll
    for (int r = 0; r < 8; ++r) a2[r] = 0.f;
    #pragma unroll 2
    for (int k = 0; k < 256; ++k) {
        float wv_ = w2[k * 256 + t];
        #pragma unroll
        for (int r = 0; r < 8; ++r) a2[r] += H1[r][k] * wv_;
    }
    float b2v = b2[t];
    #pragma unroll
    for (int r = 0; r < 8; ++r) {
        float fin = S1[r][t] + a2[r] + b2v;
        slots[((size_t)b * 8 + r) * 256 + t] = fin;
        if (last) out_slots[((size_t)b * 8 + r) * 256 + t] = fin;
    }
}

// ---------- final attn normalization ----------
__global__ __launch_bounds__(256) void k_scale(float* __restrict__ attn, const float* __restrict__ rowsum) {
    size_t idx = (size_t)blockIdx.x * 256 + threadIdx.x;  // 16,777,216
    int row = (int)(idx >> 12);
    float rs = fmaxf(rowsum[row], 1e-12f);
    attn[idx] = attn[idx] / rs;
}

extern "C" void kernel_launch(void* const* d_in, const int* in_sizes, int n_in,
                              void* d_out, int out_size, void* d_ws, size_t ws_size,
                              hipStream_t stream) {
    const float* inputs = (const float*)d_in[0];
    const float* noise  = (const float*)d_in[1];
    const float* sm     = (const float*)d_in[2];
    const float* slv    = (const float*)d_in[3];
    const float* wq     = (const float*)d_in[4];
    const float* bq     = (const float*)d_in[5];
    const float* wk     = (const float*)d_in[6];
    const float* bk     = (const float*)d_in[7];
    const float* wv     = (const float*)d_in[8];
    const float* bv     = (const float*)d_in[9];
    const float* wo     = (const float*)d_in[10];
    const float* bo     = (const float*)d_in[11];
    const float* wih    = (const float*)d_in[12];
    const float* bih    = (const float*)d_in[13];
    const float* whh    = (const float*)d_in[14];
    const float* bhh    = (const float*)d_in[15];
    const float* w1     = (const float*)d_in[16];
    const float* b1     = (const float*)d_in[17];
    const float* w2     = (const float*)d_in[18];
    const float* b2     = (const float*)d_in[19];
    const float* lniw   = (const float*)d_in[20];
    const float* lnib   = (const float*)d_in[21];
    const float* lnsw   = (const float*)d_in[22];
    const float* lnsb   = (const float*)d_in[23];
    const float* lnfw   = (const float*)d_in[24];
    const float* lnfb   = (const float*)d_in[25];

    char* ws = (char*)d_ws;
    unsigned short* Kb = (unsigned short*)ws;                         // 134,217,728 B
    unsigned short* Vb = (unsigned short*)(ws + 134217728ull);        // 134,217,728 B
    unsigned short* W3 = (unsigned short*)(ws + 268435456ull);        //     262,144 B
    float* slots   = (float*)(ws + 268697600ull);                     //     524,288 B
    float* qg      = (float*)(ws + 269221888ull);                     //     524,288 B
    float* upd_raw = (float*)(ws + 269746176ull);                     //     524,288 B
    float* rowsum  = (float*)(ws + 270270464ull);                     //      16,384 B

    float* out_slots = (float*)d_out;            // [64,8,256]
    float* attn_out  = (float*)d_out + 131072;   // [64,8,8,4096]

    k_prep<<<512, 256, 0, stream>>>(wk, wv, W3);
    k_init<<<512, 256, 0, stream>>>(sm, slv, noise, slots);
    k_kv<<<4096, 256, 0, stream>>>(inputs, lniw, lnib, W3, bk, bv, Kb, Vb);
    for (int it = 0; it < 3; ++it) {
        int last = (it == 2);
        hipMemsetAsync(upd_raw, 0, 524288 + 16384, stream);
        k_q<<<512, 256, 0, stream>>>(slots, lnsw, lnsb, wq, bq, qg);
        k_attn<<<4096, 256, 0, stream>>>(Kb, Vb, qg, upd_raw, rowsum, attn_out, last);
        k_slot<<<64, 256, 0, stream>>>(slots, upd_raw, rowsum, wo, bo, wih, bih, whh, bhh,
                                       w1, b1, w2, b2, lnfw, lnfb, out_slots, last);
    }
    k_scale<<<65536, 256, 0, stream>>>(attn_out, rowsum);
}

// Round 3
// 1189.837 us; speedup vs baseline: 1.4533x; 1.3243x over previous
//
#include <hip/hip_runtime.h>
#include <stdint.h>

// ---------- helpers ----------
typedef __attribute__((ext_vector_type(8))) short bf16x8;
typedef __attribute__((ext_vector_type(4))) float f32x4;

__device__ __forceinline__ float b2f(unsigned short s) {
    unsigned int u = ((unsigned int)s) << 16;
    return __builtin_bit_cast(float, u);
}
__device__ __forceinline__ unsigned short f2b(float f) {
    unsigned int u = __builtin_bit_cast(unsigned int, f);
    u += 0x7FFFu + ((u >> 16) & 1u);   // RNE
    return (unsigned short)(u >> 16);
}
__device__ __forceinline__ void unpack8(uint4 u, float* o) {
    unsigned int a0 = u.x, a1 = u.y, a2 = u.z, a3 = u.w;
    o[0] = __builtin_bit_cast(float, a0 << 16);
    o[1] = __builtin_bit_cast(float, a0 & 0xffff0000u);
    o[2] = __builtin_bit_cast(float, a1 << 16);
    o[3] = __builtin_bit_cast(float, a1 & 0xffff0000u);
    o[4] = __builtin_bit_cast(float, a2 << 16);
    o[5] = __builtin_bit_cast(float, a2 & 0xffff0000u);
    o[6] = __builtin_bit_cast(float, a3 << 16);
    o[7] = __builtin_bit_cast(float, a3 & 0xffff0000u);
}

#define GLOAD_LDS16(g, l) __builtin_amdgcn_global_load_lds( \
    (const __attribute__((address_space(1))) unsigned int*)(g), \
    (__attribute__((address_space(3))) unsigned int*)(l), 16, 0, 0)

#define EPS_ATTN 1e-8f
#define LN_EPS 1e-5f
#define SCALE 0.0625f  // 256^-0.5

// ---------- prep: W3 in MFMA B-fragment order ----------
__global__ __launch_bounds__(256) void k_prep(const float* __restrict__ wk,
                                              const float* __restrict__ wv,
                                              unsigned short* __restrict__ W3) {
    int g = blockIdx.x * 256 + threadIdx.x;   // 131072
    int j = g & 7;
    int f = (g >> 3) & 1023;
    int stage = g >> 13;
    int p = f & 15, qq = (f >> 4) & 3, ntl = f >> 6;
    int kc = stage >> 1, half = stage & 1;
    int k = kc * 32 + qq * 8 + j;
    int n = half * 256 + ntl * 16 + p;
    float v = (n < 256) ? wk[k * 256 + n] : wv[k * 256 + (n - 256)];
    W3[g] = f2b(v);
}

// ---------- slot init ----------
__global__ __launch_bounds__(256) void k_init(const float* __restrict__ sm,
                                              const float* __restrict__ slv,
                                              const float* __restrict__ noise,
                                              float* __restrict__ slots) {
    int idx = blockIdx.x * 256 + threadIdx.x; // 131072
    int d = idx & 255;
    slots[idx] = sm[d] + expf(slv[d]) * noise[idx];
}

// ---------- fused LN(inputs) + K/V projection (bf16 MFMA, async B staging) ----------
__global__ __launch_bounds__(256, 2) void k_kv(
    const float* __restrict__ x, const float* __restrict__ lnw, const float* __restrict__ lnb,
    const unsigned short* __restrict__ W3, const float* __restrict__ bk, const float* __restrict__ bv,
    unsigned short* __restrict__ Kb, unsigned short* __restrict__ Vb) {
    __shared__ __align__(16) unsigned short sh[33792];  // 67,584 B
    unsigned short* As = sh;                  // 16384 ushorts (A frags, xor-swizzled)
    unsigned short* Bs = sh + 16384;          // 2 x 8192 ushorts (B dbuf)
    float* bL = (float*)(sh + 32768);         // 512 floats (biases)
    int t = threadIdx.x;
    int w = t >> 6, lane = t & 63;
    int p = lane & 15, q = lane >> 4;

    {
        const unsigned short* gp = W3 + (size_t)(w * 4) * 512 + lane * 8;
        #pragma unroll
        for (int c = 0; c < 4; ++c)
            GLOAD_LDS16(gp + c * 512, Bs + (w * 4 + c) * 512);
    }
    if (t < 128) {
        float4 bb = (t < 64) ? ((const float4*)bk)[t] : ((const float4*)bv)[t - 64];
        *(float4*)&bL[t * 4] = bb;
    }

    float4 lw  = ((const float4*)lnw)[lane];
    float4 lbv = ((const float4*)lnb)[lane];
    float4 xv[16];
    const float* xbase = x + ((size_t)blockIdx.x * 64 + w * 16) * 256;
    #pragma unroll
    for (int i = 0; i < 16; ++i) xv[i] = ((const float4*)(xbase + i * 256))[lane];
    int kcw = lane >> 3, qw = (lane >> 1) & 3, j0 = (lane & 1) * 4;
    #pragma unroll
    for (int i = 0; i < 16; ++i) {
        float4 v = xv[i];
        float s0 = v.x + v.y + v.z + v.w;
        float s1 = v.x * v.x + v.y * v.y + v.z * v.z + v.w * v.w;
        #pragma unroll
        for (int o = 1; o < 64; o <<= 1) { s0 += __shfl_xor(s0, o); s1 += __shfl_xor(s1, o); }
        float mean = s0 * (1.0f / 256.0f);
        float var  = s1 * (1.0f / 256.0f) - mean * mean;
        float rstd = rsqrtf(var + LN_EPS);
        ushort4 pk;
        pk.x = f2b((v.x - mean) * rstd * lw.x + lbv.x);
        pk.y = f2b((v.y - mean) * rstd * lw.y + lbv.y);
        pk.z = f2b((v.z - mean) * rstd * lw.z + lbv.z);
        pk.w = f2b((v.w - mean) * rstd * lw.w + lbv.w);
        int pos = (qw * 16 + i) ^ kcw;
        *(ushort4*)&As[((w * 8 + kcw) * 64 + pos) * 8 + j0] = pk;
    }
    __syncthreads();

    f32x4 acc[32];
    f32x4 zero = {0.f, 0.f, 0.f, 0.f};
    #pragma unroll
    for (int i = 0; i < 32; ++i) acc[i] = zero;

    for (int s1 = 0; s1 < 16; ++s1) {
        if (s1 < 15) {
            int nx = s1 + 1;
            const unsigned short* gp = W3 + (size_t)nx * 8192 + (w * 4) * 512 + lane * 8;
            unsigned short* lb = Bs + ((nx & 1) ? 8192 : 0);
            #pragma unroll
            for (int c = 0; c < 4; ++c)
                GLOAD_LDS16(gp + c * 512, lb + (w * 4 + c) * 512);
        }
        int kc = s1 >> 1, half = s1 & 1;
        bf16x8 af = *(const bf16x8*)&As[((w * 8 + kc) * 64 + ((q * 16 + p) ^ kc)) * 8];
        const unsigned short* bbuf = Bs + ((s1 & 1) ? 8192 : 0);
        #pragma unroll
        for (int ntl = 0; ntl < 16; ++ntl) {
            bf16x8 bf = *(const bf16x8*)&bbuf[ntl * 512 + lane * 8];
            acc[half * 16 + ntl] = __builtin_amdgcn_mfma_f32_16x16x32_bf16(
                af, bf, acc[half * 16 + ntl], 0, 0, 0);
        }
        __syncthreads();
    }

    unsigned short* rep = As;
    int b_   = blockIdx.x >> 6;
    int n0g  = (blockIdx.x & 63) * 64;
    #pragma unroll
    for (int hf = 0; hf < 2; ++hf) {
        if (hf) __syncthreads();
        #pragma unroll
        for (int al = 0; al < 16; ++al) {
            int ai = hf * 16 + al;
            float bias = bL[hf * 256 + al * 16 + p];
            int hl = al >> 1, dh = (al & 1) * 16 + p;
            #pragma unroll
            for (int r = 0; r < 4; ++r) {
                int nl = w * 16 + q * 4 + r;
                rep[(hl * 64 + nl) * 32 + dh] = f2b(acc[ai][r] + bias);
            }
        }
        __syncthreads();
        unsigned short* dst = hf ? Vb : Kb;
        #pragma unroll
        for (int i = 0; i < 8; ++i) {
            uint4 vd = *(const uint4*)&rep[(i * 256 + t) * 8];
            *(uint4*)(dst + (((size_t)b_ * 8 + i) * 4096 + n0g) * 32 + t * 8) = vd;
        }
    }
}

// ---------- q projection ----------
__global__ __launch_bounds__(256) void k_q(
    const float* __restrict__ slots, const float* __restrict__ lnw, const float* __restrict__ lnb,
    const float* __restrict__ wq, const float* __restrict__ bq, float* __restrict__ qg) {
    __shared__ float sln[256];
    __shared__ float red[8];
    int t = threadIdx.x;
    int row = blockIdx.x;
    float v = slots[(size_t)row * 256 + t];
    float s0 = v, s1 = v * v;
    #pragma unroll
    for (int off = 1; off < 64; off <<= 1) { s0 += __shfl_xor(s0, off); s1 += __shfl_xor(s1, off); }
    if ((t & 63) == 0) { red[t >> 6] = s0; red[4 + (t >> 6)] = s1; }
    __syncthreads();
    float ts0 = red[0] + red[1] + red[2] + red[3];
    float ts1 = red[4] + red[5] + red[6] + red[7];
    float mean = ts0 * (1.f / 256.f);
    float var  = ts1 * (1.f / 256.f) - mean * mean;
    float rstd = rsqrtf(var + LN_EPS);
    sln[t] = (v - mean) * rstd * lnw[t] + lnb[t];
    __syncthreads();
    float acc = bq[t];
    #pragma unroll 4
    for (int k = 0; k < 256; ++k) acc += sln[k] * wq[k * 256 + t];
    int b = row >> 3, sl = row & 7;
    qg[(size_t)b * 2048 + (t >> 5) * 256 + sl * 32 + (t & 31)] = acc;
}

// ---------- attention sweep: thread-per-n ----------
__global__ __launch_bounds__(256, 3) void k_attn(
    const unsigned short* __restrict__ Kg, const unsigned short* __restrict__ Vg,
    const float* __restrict__ qg, float* __restrict__ upd_raw, float* __restrict__ rowsum,
    float* __restrict__ attn_out, int last) {
    __shared__ __align__(16) float VL[256 * 33];
    __shared__ __align__(16) float aL[8 * 264];
    __shared__ float qL[256];
    int t = threadIdx.x;
    int bh = blockIdx.x >> 3;
    int n0 = (blockIdx.x & 7) * 512;
    qL[t] = qg[bh * 256 + t];
    int s2 = t >> 5, dq = (t >> 2) & 7, jp = t & 3;
    float4 uacc = {0.f, 0.f, 0.f, 0.f};
    float rs_loc[8];
    #pragma unroll
    for (int s = 0; s < 8; ++s) rs_loc[s] = 0.f;
    __syncthreads();

    for (int st = 0; st < 2; ++st) {
        int n = n0 + st * 256 + t;
        size_t base = ((size_t)bh * 4096 + n) * 32;
        const uint4* kp = (const uint4*)(Kg + base);
        float kf[32];
        unpack8(kp[0], kf + 0); unpack8(kp[1], kf + 8);
        unpack8(kp[2], kf + 16); unpack8(kp[3], kf + 24);
        float sd[8];
        #pragma unroll
        for (int s = 0; s < 8; ++s) {
            float a = 0.f;
            #pragma unroll
            for (int d4 = 0; d4 < 8; ++d4) {
                float4 q4 = *(const float4*)&qL[s * 32 + d4 * 4];
                a = fmaf(kf[d4 * 4 + 0], q4.x, a);
                a = fmaf(kf[d4 * 4 + 1], q4.y, a);
                a = fmaf(kf[d4 * 4 + 2], q4.z, a);
                a = fmaf(kf[d4 * 4 + 3], q4.w, a);
            }
            sd[s] = a * SCALE;
        }
        float m = sd[0];
        #pragma unroll
        for (int s = 1; s < 8; ++s) m = fmaxf(m, sd[s]);
        float e[8]; float sum = 0.f;
        #pragma unroll
        for (int s = 0; s < 8; ++s) { e[s] = __expf(sd[s] - m); sum += e[s]; }
        float inv = 1.0f / sum;
        float a8[8];
        #pragma unroll
        for (int s = 0; s < 8; ++s) { a8[s] = e[s] * inv + EPS_ATTN; rs_loc[s] += a8[s]; }
        if (last) {
            #pragma unroll
            for (int s = 0; s < 8; ++s)
                attn_out[((size_t)bh * 8 + s) * 4096 + n] = a8[s];
        }
        if (st) __syncthreads();
        #pragma unroll
        for (int s = 0; s < 8; ++s) aL[s * 264 + t] = a8[s];
        const uint4* vp = (const uint4*)(Vg + base);
        float vf[32];
        unpack8(vp[0], vf + 0); unpack8(vp[1], vf + 8);
        unpack8(vp[2], vf + 16); unpack8(vp[3], vf + 24);
        #pragma unroll
        for (int d = 0; d < 32; ++d) VL[t * 33 + d] = vf[d];
        __syncthreads();
        #pragma unroll 4
        for (int j2 = 0; j2 < 64; ++j2) {
            int j = j2 * 4 + jp;
            float av = aL[s2 * 264 + j];
            int vb = j * 33 + dq * 4;
            uacc.x = fmaf(av, VL[vb + 0], uacc.x);
            uacc.y = fmaf(av, VL[vb + 1], uacc.y);
            uacc.z = fmaf(av, VL[vb + 2], uacc.z);
            uacc.w = fmaf(av, VL[vb + 3], uacc.w);
        }
    }
    uacc.x += __shfl_xor(uacc.x, 1); uacc.x += __shfl_xor(uacc.x, 2);
    uacc.y += __shfl_xor(uacc.y, 1); uacc.y += __shfl_xor(uacc.y, 2);
    uacc.z += __shfl_xor(uacc.z, 1); uacc.z += __shfl_xor(uacc.z, 2);
    uacc.w += __shfl_xor(uacc.w, 1); uacc.w += __shfl_xor(uacc.w, 2);
    if (jp == 0) {
        float* up = upd_raw + bh * 256 + s2 * 32 + dq * 4;
        atomicAdd(up + 0, uacc.x);
        atomicAdd(up + 1, uacc.y);
        atomicAdd(up + 2, uacc.z);
        atomicAdd(up + 3, uacc.w);
    }
    #pragma unroll
    for (int s = 0; s < 8; ++s) {
        float v = rs_loc[s];
        #pragma unroll
        for (int o = 1; o < 64; o <<= 1) v += __shfl_xor(v, o);
        if ((t & 63) == 0) atomicAdd(&rowsum[bh * 8 + s], v);
    }
}

// ========== slot-update stage kernels (col-split, LDS row-broadcast) ==========
// Stage A: O = U @ wo + bo.  grid 256 = b(64) x cc(4); 64 cols/block, K split 4 ways over waves.
__global__ __launch_bounds__(256) void k_gA(
    const float* __restrict__ upd_raw, const float* __restrict__ rowsum,
    const float* __restrict__ wo, const float* __restrict__ bo, float* __restrict__ O) {
    __shared__ float Ul[8][256];
    __shared__ float Pp[4][8][64];
    int t = threadIdx.x;
    int b = blockIdx.x >> 2, cc = blockIdx.x & 3;
    int colbase = cc * 64;
    {
        int r = t >> 5, d0 = (t & 31) * 8;
        int h = d0 >> 5;
        float inv = 1.0f / fmaxf(rowsum[(b * 8 + h) * 8 + r], 1e-12f);
        const float* up = upd_raw + (size_t)(b * 8 + h) * 256 + r * 32 + (d0 & 31);
        float4 u0 = *(const float4*)up;
        float4 u1 = *(const float4*)(up + 4);
        Ul[r][d0 + 0] = u0.x * inv; Ul[r][d0 + 1] = u0.y * inv;
        Ul[r][d0 + 2] = u0.z * inv; Ul[r][d0 + 3] = u0.w * inv;
        Ul[r][d0 + 4] = u1.x * inv; Ul[r][d0 + 5] = u1.y * inv;
        Ul[r][d0 + 6] = u1.z * inv; Ul[r][d0 + 7] = u1.w * inv;
    }
    __syncthreads();
    int c = t & 63, kq = t >> 6;
    float acc[8] = {0.f,0.f,0.f,0.f,0.f,0.f,0.f,0.f};
    const float* wp = wo + (size_t)(kq * 64) * 256 + colbase + c;
    #pragma unroll 16
    for (int k = 0; k < 64; ++k) {
        float wv_ = wp[(size_t)k * 256];
        int kk = kq * 64 + k;
        #pragma unroll
        for (int r = 0; r < 8; ++r) acc[r] += Ul[r][kk] * wv_;
    }
    #pragma unroll
    for (int r = 0; r < 8; ++r) Pp[kq][r][c] = acc[r];
    __syncthreads();
    #pragma unroll
    for (int j = 0; j < 2; ++j) {
        int o = t * 2 + j;
        int r = o >> 6, c2 = o & 63;
        float v = Pp[0][r][c2] + Pp[1][r][c2] + Pp[2][r][c2] + Pp[3][r][c2] + bo[colbase + c2];
        O[(size_t)(b * 8 + r) * 256 + colbase + c2] = v;
    }
}

// Stage B: xg = O@wih+bih, hg = Hp@whh+bhh. grid 384 = b(64) x cc(6); 128 cols/block, K split 2.
// cols 0..511 -> gcomb (xr+hr, xz+hz); cols 512..767 -> xn, hn separate.
__global__ __launch_bounds__(256) void k_gB(
    const float* __restrict__ O, const float* __restrict__ slin,
    const float* __restrict__ wih, const float* __restrict__ bih,
    const float* __restrict__ whh, const float* __restrict__ bhh,
    float* __restrict__ gcomb, float* __restrict__ xn, float* __restrict__ hn) {
    __shared__ float Ol[8][256], Hl[8][256];
    __shared__ float Px[2][8][128], Ph[2][8][128];
    int t = threadIdx.x;
    int b = blockIdx.x / 6, cc = blockIdx.x % 6;
    int colbase = cc * 128;
    {
        int r = t >> 5, d0 = (t & 31) * 8;
        const float* op = O + (size_t)(b * 8 + r) * 256 + d0;
        const float* hp = slin + (size_t)(b * 8 + r) * 256 + d0;
        *(float4*)&Ol[r][d0]     = *(const float4*)op;
        *(float4*)&Ol[r][d0 + 4] = *(const float4*)(op + 4);
        *(float4*)&Hl[r][d0]     = *(const float4*)hp;
        *(float4*)&Hl[r][d0 + 4] = *(const float4*)(hp + 4);
    }
    __syncthreads();
    int c = t & 127, kh = t >> 7;
    float ax[8] = {0.f,0.f,0.f,0.f,0.f,0.f,0.f,0.f};
    float ah[8] = {0.f,0.f,0.f,0.f,0.f,0.f,0.f,0.f};
    const float* wxp = wih + (size_t)(kh * 128) * 768 + colbase + c;
    const float* whp = whh + (size_t)(kh * 128) * 768 + colbase + c;
    #pragma unroll 8
    for (int k = 0; k < 128; ++k) {
        float wx = wxp[(size_t)k * 768];
        float wh = whp[(size_t)k * 768];
        int kk = kh * 128 + k;
        #pragma unroll
        for (int r = 0; r < 8; ++r) { ax[r] += Ol[r][kk] * wx; ah[r] += Hl[r][kk] * wh; }
    }
    #pragma unroll
    for (int r = 0; r < 8; ++r) { Px[kh][r][c] = ax[r]; Ph[kh][r][c] = ah[r]; }
    __syncthreads();
    #pragma unroll
    for (int j = 0; j < 4; ++j) {
        int o = t * 4 + j;               // [0,1024)
        int r = o >> 7, c2 = o & 127;
        int cg = colbase + c2;
        int row = b * 8 + r;
        float vx = Px[0][r][c2] + Px[1][r][c2] + bih[cg];
        float vh = Ph[0][r][c2] + Ph[1][r][c2] + bhh[cg];
        if (cg < 512) {
            gcomb[(size_t)row * 512 + cg] = vx + vh;
        } else {
            xn[(size_t)row * 256 + cg - 512] = vx;
            hn[(size_t)row * 256 + cg - 512] = vh;
        }
    }
}

// Stage C: gates -> S1 (stored into slout), LN(S1) -> F.  grid 512 rows.
__global__ __launch_bounds__(256) void k_gC(
    const float* __restrict__ gcomb, const float* __restrict__ xn, const float* __restrict__ hn,
    const float* __restrict__ slin, const float* __restrict__ lnfw, const float* __restrict__ lnfb,
    float* __restrict__ slout, float* __restrict__ F) {
    __shared__ float red[8];
    int t = threadIdx.x, row = blockIdx.x;
    float a_r = gcomb[(size_t)row * 512 + t];
    float a_z = gcomb[(size_t)row * 512 + 256 + t];
    float xnv = xn[(size_t)row * 256 + t];
    float hnv = hn[(size_t)row * 256 + t];
    float hp  = slin[(size_t)row * 256 + t];
    float rg = 1.f / (1.f + expf(-a_r));
    float zg = 1.f / (1.f + expf(-a_z));
    float ng = tanhf(xnv + rg * hnv);
    float s1 = (1.f - zg) * ng + zg * hp;
    slout[(size_t)row * 256 + t] = s1;
    float s0 = s1, sq = s1 * s1;
    #pragma unroll
    for (int o = 1; o < 64; o <<= 1) { s0 += __shfl_xor(s0, o); sq += __shfl_xor(sq, o); }
    if ((t & 63) == 0) { red[t >> 6] = s0; red[4 + (t >> 6)] = sq; }
    __syncthreads();
    float ts0 = red[0] + red[1] + red[2] + red[3];
    float ts1 = red[4] + red[5] + red[6] + red[7];
    float mean = ts0 * (1.f / 256.f);
    float var  = ts1 * (1.f / 256.f) - mean * mean;
    float rstd = rsqrtf(var + LN_EPS);
    F[(size_t)row * 256 + t] = (s1 - mean) * rstd * lnfw[t] + lnfb[t];
}

// Stage D: H1 = relu(F @ w1 + b1).  grid 256 = b x cc(4).
__global__ __launch_bounds__(256) void k_gD(
    const float* __restrict__ F, const float* __restrict__ w1, const float* __restrict__ b1,
    float* __restrict__ H1) {
    __shared__ float Fl[8][256];
    __shared__ float Pp[4][8][64];
    int t = threadIdx.x;
    int b = blockIdx.x >> 2, cc = blockIdx.x & 3;
    int colbase = cc * 64;
    {
        int r = t >> 5, d0 = (t & 31) * 8;
        const float* fp = F + (size_t)(b * 8 + r) * 256 + d0;
        *(float4*)&Fl[r][d0]     = *(const float4*)fp;
        *(float4*)&Fl[r][d0 + 4] = *(const float4*)(fp + 4);
    }
    __syncthreads();
    int c = t & 63, kq = t >> 6;
    float acc[8] = {0.f,0.f,0.f,0.f,0.f,0.f,0.f,0.f};
    const float* wp = w1 + (size_t)(kq * 64) * 256 + colbase + c;
    #pragma unroll 16
    for (int k = 0; k < 64; ++k) {
        float wv_ = wp[(size_t)k * 256];
        int kk = kq * 64 + k;
        #pragma unroll
        for (int r = 0; r < 8; ++r) acc[r] += Fl[r][kk] * wv_;
    }
    #pragma unroll
    for (int r = 0; r < 8; ++r) Pp[kq][r][c] = acc[r];
    __syncthreads();
    #pragma unroll
    for (int j = 0; j < 2; ++j) {
        int o = t * 2 + j;
        int r = o >> 6, c2 = o & 63;
        float v = Pp[0][r][c2] + Pp[1][r][c2] + Pp[2][r][c2] + Pp[3][r][c2] + b1[colbase + c2];
        H1[(size_t)(b * 8 + r) * 256 + colbase + c2] = fmaxf(v, 0.f);
    }
}

// Stage E: slout = S1 + H1 @ w2 + b2 (S1 already resident in slout).  grid 256.
__global__ __launch_bounds__(256) void k_gE(
    const float* __restrict__ H1, const float* __restrict__ w2, const float* __restrict__ b2,
    float* __restrict__ slout) {
    __shared__ float Hl[8][256];
    __shared__ float Pp[4][8][64];
    int t = threadIdx.x;
    int b = blockIdx.x >> 2, cc = blockIdx.x & 3;
    int colbase = cc * 64;
    {
        int r = t >> 5, d0 = (t & 31) * 8;
        const float* hp = H1 + (size_t)(b * 8 + r) * 256 + d0;
        *(float4*)&Hl[r][d0]     = *(const float4*)hp;
        *(float4*)&Hl[r][d0 + 4] = *(const float4*)(hp + 4);
    }
    __syncthreads();
    int c = t & 63, kq = t >> 6;
    float acc[8] = {0.f,0.f,0.f,0.f,0.f,0.f,0.f,0.f};
    const float* wp = w2 + (size_t)(kq * 64) * 256 + colbase + c;
    #pragma unroll 16
    for (int k = 0; k < 64; ++k) {
        float wv_ = wp[(size_t)k * 256];
        int kk = kq * 64 + k;
        #pragma unroll
        for (int r = 0; r < 8; ++r) acc[r] += Hl[r][kk] * wv_;
    }
    #pragma unroll
    for (int r = 0; r < 8; ++r) Pp[kq][r][c] = acc[r];
    __syncthreads();
    #pragma unroll
    for (int j = 0; j < 2; ++j) {
        int o = t * 2 + j;
        int r = o >> 6, c2 = o & 63;
        size_t idx = (size_t)(b * 8 + r) * 256 + colbase + c2;
        float v = Pp[0][r][c2] + Pp[1][r][c2] + Pp[2][r][c2] + Pp[3][r][c2] + b2[colbase + c2];
        slout[idx] = slout[idx] + v;
    }
}

// ---------- final attn normalization ----------
__global__ __launch_bounds__(256) void k_scale(float* __restrict__ attn, const float* __restrict__ rowsum) {
    size_t idx = (size_t)blockIdx.x * 256 + threadIdx.x;
    int row = (int)(idx >> 12);
    float rs = fmaxf(rowsum[row], 1e-12f);
    attn[idx] = attn[idx] / rs;
}

extern "C" void kernel_launch(void* const* d_in, const int* in_sizes, int n_in,
                              void* d_out, int out_size, void* d_ws, size_t ws_size,
                              hipStream_t stream) {
    const float* inputs = (const float*)d_in[0];
    const float* noise  = (const float*)d_in[1];
    const float* sm     = (const float*)d_in[2];
    const float* slv    = (const float*)d_in[3];
    const float* wq     = (const float*)d_in[4];
    const float* bq     = (const float*)d_in[5];
    const float* wk     = (const float*)d_in[6];
    const float* bk     = (const float*)d_in[7];
    const float* wv     = (const float*)d_in[8];
    const float* bv     = (const float*)d_in[9];
    const float* wo     = (const float*)d_in[10];
    const float* bo     = (const float*)d_in[11];
    const float* wih    = (const float*)d_in[12];
    const float* bih    = (const float*)d_in[13];
    const float* whh    = (const float*)d_in[14];
    const float* bhh    = (const float*)d_in[15];
    const float* w1     = (const float*)d_in[16];
    const float* b1     = (const float*)d_in[17];
    const float* w2     = (const float*)d_in[18];
    const float* b2     = (const float*)d_in[19];
    const float* lniw   = (const float*)d_in[20];
    const float* lnib   = (const float*)d_in[21];
    const float* lnsw   = (const float*)d_in[22];
    const float* lnsb   = (const float*)d_in[23];
    const float* lnfw   = (const float*)d_in[24];
    const float* lnfb   = (const float*)d_in[25];

    // ws layout (~273.2 MB), with aliasing:
    //  P region: W3 (prep/kv) then O (gA->gB)
    //  Q region: gcomb+xn+hn (gB->gC) then H1 (gD->gE)
    //  R region: qg (k_q->k_attn) then F (gC->gD)
    char* ws = (char*)d_ws;
    unsigned short* Kb = (unsigned short*)ws;                         // 134,217,728
    unsigned short* Vb = (unsigned short*)(ws + 134217728ull);        // 134,217,728
    float* slotsA  = (float*)(ws + 268435456ull);                     // 524,288
    float* slotsB  = (float*)(ws + 268959744ull);                     // 524,288
    float* Rr      = (float*)(ws + 269484032ull);                     // 524,288  (qg / F)
    float* Pr      = (float*)(ws + 270008320ull);                     // 524,288  (W3 / O)
    float* Qr      = (float*)(ws + 270532608ull);                     // 2,097,152 (gcomb|xn|hn / H1)
    float* upd_raw = (float*)(ws + 272629760ull);                     // 524,288
    float* rowsum  = (float*)(ws + 273154048ull);                     // 16,384
    unsigned short* W3 = (unsigned short*)Pr;
    float* O_  = Pr;
    float* gcomb = Qr;                    // 512x512
    float* xn = Qr + 262144;              // 512x256
    float* hn = Qr + 393216;              // 512x256
    float* H1 = Qr;                       // 512x256 (aliases gcomb, gB->gC dead by gD)
    float* qg = Rr;
    float* F_ = Rr;

    float* out_slots = (float*)d_out;            // [64,8,256]
    float* attn_out  = (float*)d_out + 131072;   // [64,8,8,4096]

    k_prep<<<512, 256, 0, stream>>>(wk, wv, W3);
    k_init<<<512, 256, 0, stream>>>(sm, slv, noise, slotsA);
    k_kv<<<4096, 256, 0, stream>>>(inputs, lniw, lnib, W3, bk, bv, Kb, Vb);
    for (int it = 0; it < 3; ++it) {
        int last = (it == 2);
        float* sl_in  = (it == 0) ? slotsA : ((it == 1) ? slotsB : slotsA);
        float* sl_out = (it == 0) ? slotsB : ((it == 1) ? slotsA : out_slots);
        hipMemsetAsync(upd_raw, 0, 524288 + 16384, stream);
        k_q<<<512, 256, 0, stream>>>(sl_in, lnsw, lnsb, wq, bq, qg);
        k_attn<<<4096, 256, 0, stream>>>(Kb, Vb, qg, upd_raw, rowsum, attn_out, last);
        k_gA<<<256, 256, 0, stream>>>(upd_raw, rowsum, wo, bo, O_);
        k_gB<<<384, 256, 0, stream>>>(O_, sl_in, wih, bih, whh, bhh, gcomb, xn, hn);
        k_gC<<<512, 256, 0, stream>>>(gcomb, xn, hn, sl_in, lnfw, lnfb, sl_out, F_);
        k_gD<<<256, 256, 0, stream>>>(F_, w1, b1, H1);
        k_gE<<<256, 256, 0, stream>>>(H1, w2, b2, sl_out);
    }
    k_scale<<<65536, 256, 0, stream>>>(attn_out, rowsum);
}